// Round 5
// baseline (624.612 us; speedup 1.0000x reference)
//
#include <hip/hip_runtime.h>
#include <stdint.h>

#define D_MODEL 1024
#define D_HIDDEN 4096
#define NUM_EXPERTS 8
#define NTOK 4096  // B*T = 2*2048
#define MAXSLOT 40 // sum_e ceil(cnt_e/128) <= 32+7 = 39
#define KSPLIT 4   // ffn2 split-K chunks (K=4096 -> 1024 each)

typedef __bf16 bf16x8 __attribute__((ext_vector_type(8)));
typedef float floatx4 __attribute__((ext_vector_type(4)));

typedef const __attribute__((address_space(1))) void* gas_t;
typedef __attribute__((address_space(3))) void* las_t;

// async 16-B-per-lane global->LDS copy (wave: lds dest = base + lane*16)
static __device__ __forceinline__ void async_copy16(const void* g, void* l) {
    __builtin_amdgcn_global_load_lds((gas_t)g, (las_t)l, 16, 0, 0);
}

static __device__ __forceinline__ unsigned short f2bf(float f) {
    union { float f; unsigned int i; } v;
    v.f = f;
    unsigned int i = v.i;
    unsigned int r = (i + 0x7fffu + ((i >> 16) & 1u)) >> 16;  // RNE
    return (unsigned short)r;
}

// ---------------------------------------------------------------------------
// Gating (fp32): one wave per token, 4 waves/block.
// ---------------------------------------------------------------------------
__global__ __launch_bounds__(256) void gate_kernel(
    const float* __restrict__ x, const float* __restrict__ Wg,
    const float* __restrict__ bg, int* __restrict__ counts,
    int* __restrict__ tlist, float* __restrict__ wgt)
{
    const int wave = threadIdx.x >> 6;
    const int lane = threadIdx.x & 63;
    const int tok = blockIdx.x * 4 + wave;

    float acc[NUM_EXPERTS];
#pragma unroll
    for (int e = 0; e < NUM_EXPERTS; e++) acc[e] = 0.f;

    const float* xr = x + (size_t)tok * D_MODEL;
    for (int d = lane; d < D_MODEL; d += 64) {
        float xv = xr[d];
        const float4* wr = (const float4*)(Wg + (size_t)d * NUM_EXPERTS);
        float4 w0 = wr[0], w1 = wr[1];
        acc[0] += xv * w0.x; acc[1] += xv * w0.y;
        acc[2] += xv * w0.z; acc[3] += xv * w0.w;
        acc[4] += xv * w1.x; acc[5] += xv * w1.y;
        acc[6] += xv * w1.z; acc[7] += xv * w1.w;
    }
#pragma unroll
    for (int e = 0; e < NUM_EXPERTS; e++) {
        float v = acc[e];
#pragma unroll
        for (int off = 32; off > 0; off >>= 1) v += __shfl_xor(v, off, 64);
        acc[e] = v;
    }
    if (lane == 0) {
        float lg[NUM_EXPERTS];
#pragma unroll
        for (int e = 0; e < NUM_EXPERTS; e++) lg[e] = acc[e] + bg[e];
        int amax = 0;
        float m = lg[0];
#pragma unroll
        for (int e = 1; e < NUM_EXPERTS; e++) {
            if (lg[e] > m) { m = lg[e]; amax = e; }  // first-index-wins
        }
        float s = 0.f;
#pragma unroll
        for (int e = 0; e < NUM_EXPERTS; e++) s += __expf(lg[e] - m);
        wgt[tok] = 1.0f / s;
        int pos = atomicAdd(&counts[amax], 1);
        tlist[amax * NTOK + pos] = tok;
    }
}

// ---------------------------------------------------------------------------
// Pre-pass: W [E][K][N] fp32 -> Wt [E][N][K] bf16.  64x64 LDS tile.
// ---------------------------------------------------------------------------
__global__ __launch_bounds__(256) void cvt_transpose(
    const float* __restrict__ W, unsigned short* __restrict__ Wt,
    int K, int N)
{
    __shared__ unsigned short tile[64][68];
    const float* We = W + (size_t)blockIdx.z * K * N;
    unsigned short* Wte = Wt + (size_t)blockIdx.z * K * N;
    const int kb = blockIdx.y * 64, nb = blockIdx.x * 64;
    const int t = threadIdx.x;

    const int kr = t >> 4, nc = (t & 15) * 4;
#pragma unroll
    for (int s = 0; s < 4; s++) {
        int k = kr + s * 16;
        float4 v = *(const float4*)(We + (size_t)(kb + k) * N + nb + nc);
        unsigned short p[4] = {f2bf(v.x), f2bf(v.y), f2bf(v.z), f2bf(v.w)};
        *(uint2*)(&tile[k][nc]) = *(const uint2*)p;
    }
    __syncthreads();

    const int n = t >> 2, kc = (t & 3) * 16;
    unsigned short o[16];
#pragma unroll
    for (int j = 0; j < 16; j++) o[j] = tile[kc + j][n];
    unsigned short* dst = Wte + (size_t)(nb + n) * K + kb + kc;
    *(uint4*)(dst)     = ((const uint4*)o)[0];
    *(uint4*)(dst + 8) = ((const uint4*)o)[1];
}

// ---------------------------------------------------------------------------
// tile-slot -> (expert, m_tile, count), 128-row granularity.
// ---------------------------------------------------------------------------
__device__ __forceinline__ bool slot_to_expert(const int* counts, int slot,
                                               int& e_out, int& mt_out, int& cnt_out) {
    int cum = 0;
    for (int i = 0; i < NUM_EXPERTS; i++) {
        int c = counts[i];
        int t = (c + 127) >> 7;
        if (slot < cum + t) {
            e_out = i; mt_out = slot - cum; cnt_out = c;
            return true;
        }
        cum += t;
    }
    return false;
}

// ===========================================================================
// FAST PATH (bf16 transposed weights in ws)
// ===========================================================================

// FFN1: h = silu(x @ W1[e] + b1[e]).  A: fp32 x -> cvt -> LDS.  B: W1t bf16
// [n][k] via global_load_lds dwordx4.  128x128 tile, BK=32, LDS pitch 32.
__global__ __launch_bounds__(256) void ffn1_fast(
    const float* __restrict__ x,
    const unsigned short* __restrict__ W1t,  // [E][D_HIDDEN][D_MODEL] bf16
    const float* __restrict__ b1,
    const int* __restrict__ counts,
    const int* __restrict__ tlist,
    unsigned short* __restrict__ h)
{
    int e, mt, cnt;
    if (!slot_to_expert(counts, blockIdx.y, e, mt, cnt)) return;
    const int n0 = blockIdx.x * 128;

    __shared__ __align__(16) unsigned short As[128 * 32];
    __shared__ __align__(16) unsigned short Bs[128 * 32];
    __shared__ int toks[128];

    const int tid = threadIdx.x;
    if (tid < 128) {
        int r = mt * 128 + tid;
        toks[tid] = (r < cnt) ? tlist[e * NTOK + r] : -1;
    }
    __syncthreads();

    const int wave = tid >> 6, lane = tid & 63;
    const int quad = lane >> 4, lm = lane & 15;
    const int mo = (wave & 1) * 64, no = (wave >> 1) * 64;

    floatx4 acc[4][4];
#pragma unroll
    for (int i = 0; i < 4; i++)
#pragma unroll
        for (int j = 0; j < 4; j++) acc[i][j] = (floatx4){0.f, 0.f, 0.f, 0.f};

    const unsigned short* W1te = W1t + (size_t)e * D_MODEL * D_HIDDEN;

    // A: thread -> (row = tid/2, 16-float half = tid&1)
    const int arow = tid >> 1, ahalf = tid & 1;
    int atok = toks[arow];
    const float* aptr = x + (size_t)(atok < 0 ? 0 : atok) * D_MODEL + ahalf * 16;
    // B: wave handles rows [wave*32, wave*32+32): 2 async copies of 16 rows.
    const int brb0 = wave * 32;            // row base, instr 0 (+16 for instr 1)
    const int brl = lane >> 2;             // row within 16-row group
    const int bkp = (lane & 3) * 8;        // k-part

    for (int k0 = 0; k0 < D_MODEL; k0 += 32) {
        // B async: W1t row n0+rb+brl, cols k0+bkp.. (bf16, 8 = 16 B)
#pragma unroll
        for (int i = 0; i < 2; i++) {
            int rb = brb0 + i * 16;
            const unsigned short* gp =
                W1te + (size_t)(n0 + rb + brl) * D_MODEL + k0 + bkp;
            async_copy16(gp, &Bs[rb * 32]);
        }
        // A: 16 fp32 -> 16 bf16 -> 2 ds_write_b128
        float4 a4[4];
#pragma unroll
        for (int i = 0; i < 4; i++) a4[i] = ((const float4*)(aptr + k0))[i];
        unsigned short av[16];
#pragma unroll
        for (int i = 0; i < 4; i++) {
            av[i * 4 + 0] = f2bf(a4[i].x); av[i * 4 + 1] = f2bf(a4[i].y);
            av[i * 4 + 2] = f2bf(a4[i].z); av[i * 4 + 3] = f2bf(a4[i].w);
        }
        *(uint4*)(&As[arow * 32 + ahalf * 16])     = ((const uint4*)av)[0];
        *(uint4*)(&As[arow * 32 + ahalf * 16 + 8]) = ((const uint4*)av)[1];
        __syncthreads();  // drains vmcnt (async copies) + lgkmcnt

        bf16x8 af[4], bfr[4];
#pragma unroll
        for (int i = 0; i < 4; i++) {
            af[i]  = *(const bf16x8*)(&As[(mo + i * 16 + lm) * 32 + quad * 8]);
            bfr[i] = *(const bf16x8*)(&Bs[(no + i * 16 + lm) * 32 + quad * 8]);
        }
#pragma unroll
        for (int mi = 0; mi < 4; mi++)
#pragma unroll
            for (int ni = 0; ni < 4; ni++)
                acc[mi][ni] = __builtin_amdgcn_mfma_f32_16x16x32_bf16(
                    af[mi], bfr[ni], acc[mi][ni], 0, 0, 0);
        __syncthreads();
    }

    const float* b1e = b1 + (size_t)e * D_HIDDEN;
#pragma unroll
    for (int ni = 0; ni < 4; ni++) {
        int n = n0 + no + ni * 16 + lm;
        float bias = b1e[n];
#pragma unroll
        for (int mi = 0; mi < 4; mi++)
#pragma unroll
            for (int r = 0; r < 4; r++) {
                int m = mo + mi * 16 + quad * 4 + r;
                int tk = toks[m];
                if (tk >= 0) {
                    float z = acc[mi][ni][r] + bias;
                    h[(size_t)tk * D_HIDDEN + n] = f2bf(z / (1.f + __expf(-z)));
                }
            }
    }
}

// FFN2 (split-K): A = h bf16 (gathered rows) and B = W2t bf16, both staged
// via global_load_lds dwordx4.  atomicAdd epilogue into pre-zeroed out.
__global__ __launch_bounds__(256) void ffn2_fast(
    const unsigned short* __restrict__ h,
    const unsigned short* __restrict__ W2t,  // [E][D_MODEL][D_HIDDEN] bf16
    const float* __restrict__ b2,
    const int* __restrict__ counts,
    const int* __restrict__ tlist,
    const float* __restrict__ wgt,
    float* __restrict__ out)
{
    int e, mt, cnt;
    if (!slot_to_expert(counts, blockIdx.y, e, mt, cnt)) return;
    const int n0 = blockIdx.x * 128;
    const int kbeg = blockIdx.z * (D_HIDDEN / KSPLIT);
    const int kend = kbeg + (D_HIDDEN / KSPLIT);

    __shared__ __align__(16) unsigned short As[128 * 32];
    __shared__ __align__(16) unsigned short Bs[128 * 32];
    __shared__ int toks[128];

    const int tid = threadIdx.x;
    if (tid < 128) {
        int r = mt * 128 + tid;
        toks[tid] = (r < cnt) ? tlist[e * NTOK + r] : -1;
    }
    __syncthreads();

    const int wave = tid >> 6, lane = tid & 63;
    const int quad = lane >> 4, lm = lane & 15;
    const int mo = (wave & 1) * 64, no = (wave >> 1) * 64;

    floatx4 acc[4][4];
#pragma unroll
    for (int i = 0; i < 4; i++)
#pragma unroll
        for (int j = 0; j < 4; j++) acc[i][j] = (floatx4){0.f, 0.f, 0.f, 0.f};

    const unsigned short* W2te = W2t + (size_t)e * D_HIDDEN * D_MODEL;

    const int rb0 = wave * 32;       // this wave's 32-row slice (A and B)
    const int rl = lane >> 2;        // row within 16-row group
    const int kp = (lane & 3) * 8;   // k-part (8 bf16 = 16 B)

    // gathered A-row pointers (per-lane global addresses are allowed)
    int ta0 = toks[rb0 + rl];        if (ta0 < 0) ta0 = 0;
    int ta1 = toks[rb0 + 16 + rl];   if (ta1 < 0) ta1 = 0;
    const unsigned short* ap0 = h + (size_t)ta0 * D_HIDDEN + kp;
    const unsigned short* ap1 = h + (size_t)ta1 * D_HIDDEN + kp;

    for (int k0 = kbeg; k0 < kend; k0 += 32) {
        async_copy16(ap0 + k0, &As[rb0 * 32]);
        async_copy16(ap1 + k0, &As[(rb0 + 16) * 32]);
#pragma unroll
        for (int i = 0; i < 2; i++) {
            int rb = rb0 + i * 16;
            const unsigned short* gp =
                W2te + (size_t)(n0 + rb + rl) * D_HIDDEN + k0 + kp;
            async_copy16(gp, &Bs[rb * 32]);
        }
        __syncthreads();

        bf16x8 af[4], bfr[4];
#pragma unroll
        for (int i = 0; i < 4; i++) {
            af[i]  = *(const bf16x8*)(&As[(mo + i * 16 + lm) * 32 + quad * 8]);
            bfr[i] = *(const bf16x8*)(&Bs[(no + i * 16 + lm) * 32 + quad * 8]);
        }
#pragma unroll
        for (int mi = 0; mi < 4; mi++)
#pragma unroll
            for (int ni = 0; ni < 4; ni++)
                acc[mi][ni] = __builtin_amdgcn_mfma_f32_16x16x32_bf16(
                    af[mi], bfr[ni], acc[mi][ni], 0, 0, 0);
        __syncthreads();
    }

    const float* b2e = b2 + (size_t)e * D_MODEL;
#pragma unroll
    for (int ni = 0; ni < 4; ni++) {
        int n = n0 + no + ni * 16 + lm;
        float bias = (blockIdx.z == 0) ? b2e[n] : 0.f;
#pragma unroll
        for (int mi = 0; mi < 4; mi++)
#pragma unroll
            for (int r = 0; r < 4; r++) {
                int m = mo + mi * 16 + quad * 4 + r;
                int tk = toks[m];
                if (tk >= 0) {
                    atomicAdd(&out[(size_t)tk * D_MODEL + n],
                              (acc[mi][ni][r] + bias) * wgt[tk]);
                }
            }
    }
}

// ===========================================================================
// FALLBACK PATH (round-4 kernels, used only if ws_size is too small)
// ===========================================================================
__global__ __launch_bounds__(256) void ffn1_fb(
    const float* __restrict__ x, const float* __restrict__ W1,
    const float* __restrict__ b1, const int* __restrict__ counts,
    const int* __restrict__ tlist, unsigned short* __restrict__ h)
{
    int e, mt, cnt;
    if (!slot_to_expert(counts, blockIdx.y, e, mt, cnt)) return;
    const int n0 = blockIdx.x * 128;
    __shared__ __align__(16) unsigned short As[128][40];
    __shared__ __align__(16) unsigned short Bs[128][40];
    __shared__ int toks[128];
    const int tid = threadIdx.x;
    if (tid < 128) {
        int r = mt * 128 + tid;
        toks[tid] = (r < cnt) ? tlist[e * NTOK + r] : -1;
    }
    __syncthreads();
    const int wave = tid >> 6, lane = tid & 63;
    const int quad = lane >> 4, lm = lane & 15;
    const int mo = (wave & 1) * 64, no = (wave >> 1) * 64;
    floatx4 acc[4][4];
#pragma unroll
    for (int i = 0; i < 4; i++)
#pragma unroll
        for (int j = 0; j < 4; j++) acc[i][j] = (floatx4){0.f, 0.f, 0.f, 0.f};
    const float* W1e = W1 + (size_t)e * D_MODEL * D_HIDDEN;
    const int arow = tid >> 1, ahalf = tid & 1;
    int atok = toks[arow];
    const float* aptr = x + (size_t)(atok < 0 ? 0 : atok) * D_MODEL + ahalf * 16;
    const int bn = tid & 127, bg0 = tid >> 7;
    for (int k0 = 0; k0 < D_MODEL; k0 += 32) {
        float4 a4[4];
#pragma unroll
        for (int i = 0; i < 4; i++) a4[i] = ((const float4*)(aptr + k0))[i];
        unsigned short av[16];
#pragma unroll
        for (int i = 0; i < 4; i++) {
            av[i * 4 + 0] = f2bf(a4[i].x); av[i * 4 + 1] = f2bf(a4[i].y);
            av[i * 4 + 2] = f2bf(a4[i].z); av[i * 4 + 3] = f2bf(a4[i].w);
        }
        *(uint4*)(&As[arow][ahalf * 16])     = ((const uint4*)av)[0];
        *(uint4*)(&As[arow][ahalf * 16 + 8]) = ((const uint4*)av)[1];
#pragma unroll
        for (int t = 0; t < 2; t++) {
            int g = bg0 + t * 2;
            const float* bp = W1e + (size_t)(k0 + g * 8) * D_HIDDEN + n0 + bn;
            unsigned short bv[8];
#pragma unroll
            for (int j = 0; j < 8; j++) bv[j] = f2bf(bp[(size_t)j * D_HIDDEN]);
            *(uint4*)(&Bs[bn][g * 8]) = *(const uint4*)bv;
        }
        __syncthreads();
        bf16x8 af[4], bfr[4];
#pragma unroll
        for (int i = 0; i < 4; i++) {
            af[i]  = *(const bf16x8*)(&As[mo + i * 16 + lm][quad * 8]);
            bfr[i] = *(const bf16x8*)(&Bs[no + i * 16 + lm][quad * 8]);
        }
#pragma unroll
        for (int mi = 0; mi < 4; mi++)
#pragma unroll
            for (int ni = 0; ni < 4; ni++)
                acc[mi][ni] = __builtin_amdgcn_mfma_f32_16x16x32_bf16(
                    af[mi], bfr[ni], acc[mi][ni], 0, 0, 0);
        __syncthreads();
    }
    const float* b1e = b1 + (size_t)e * D_HIDDEN;
#pragma unroll
    for (int ni = 0; ni < 4; ni++) {
        int n = n0 + no + ni * 16 + lm;
        float bias = b1e[n];
#pragma unroll
        for (int mi = 0; mi < 4; mi++)
#pragma unroll
            for (int r = 0; r < 4; r++) {
                int m = mo + mi * 16 + quad * 4 + r;
                int tk = toks[m];
                if (tk >= 0) {
                    float z = acc[mi][ni][r] + bias;
                    h[(size_t)tk * D_HIDDEN + n] = f2bf(z / (1.f + __expf(-z)));
                }
            }
    }
}

__global__ __launch_bounds__(256) void ffn2_fb(
    const unsigned short* __restrict__ h, const float* __restrict__ W2,
    const float* __restrict__ b2, const int* __restrict__ counts,
    const int* __restrict__ tlist, const float* __restrict__ wgt,
    float* __restrict__ out)
{
    int e, mt, cnt;
    if (!slot_to_expert(counts, blockIdx.y, e, mt, cnt)) return;
    const int n0 = blockIdx.x * 128;
    const int kbeg = blockIdx.z * (D_HIDDEN / KSPLIT);
    const int kend = kbeg + (D_HIDDEN / KSPLIT);
    __shared__ __align__(16) unsigned short As[128][40];
    __shared__ __align__(16) unsigned short Bs[128][40];
    __shared__ int toks[128];
    const int tid = threadIdx.x;
    if (tid < 128) {
        int r = mt * 128 + tid;
        toks[tid] = (r < cnt) ? tlist[e * NTOK + r] : -1;
    }
    __syncthreads();
    const int wave = tid >> 6, lane = tid & 63;
    const int quad = lane >> 4, lm = lane & 15;
    const int mo = (wave & 1) * 64, no = (wave >> 1) * 64;
    floatx4 acc[4][4];
#pragma unroll
    for (int i = 0; i < 4; i++)
#pragma unroll
        for (int j = 0; j < 4; j++) acc[i][j] = (floatx4){0.f, 0.f, 0.f, 0.f};
    const float* W2e = W2 + (size_t)e * D_HIDDEN * D_MODEL;
    const int arow = tid >> 1, ahalf = tid & 1;
    int atok = toks[arow];
    const unsigned short* aptr =
        h + (size_t)(atok < 0 ? 0 : atok) * D_HIDDEN + ahalf * 16;
    const int bn = tid & 127, bg0 = tid >> 7;
    for (int k0 = kbeg; k0 < kend; k0 += 32) {
        uint4 a0 = *(const uint4*)(aptr + k0);
        uint4 a1 = *(const uint4*)(aptr + k0 + 8);
        *(uint4*)(&As[arow][ahalf * 16])     = a0;
        *(uint4*)(&As[arow][ahalf * 16 + 8]) = a1;
#pragma unroll
        for (int t = 0; t < 2; t++) {
            int g = bg0 + t * 2;
            const float* bp = W2e + (size_t)(k0 + g * 8) * D_MODEL + n0 + bn;
            unsigned short bv[8];
#pragma unroll
            for (int j = 0; j < 8; j++) bv[j] = f2bf(bp[(size_t)j * D_MODEL]);
            *(uint4*)(&Bs[bn][g * 8]) = *(const uint4*)bv;
        }
        __syncthreads();
        bf16x8 af[4], bfr[4];
#pragma unroll
        for (int i = 0; i < 4; i++) {
            af[i]  = *(const bf16x8*)(&As[mo + i * 16 + lm][quad * 8]);
            bfr[i] = *(const bf16x8*)(&Bs[no + i * 16 + lm][quad * 8]);
        }
#pragma unroll
        for (int mi = 0; mi < 4; mi++)
#pragma unroll
            for (int ni = 0; ni < 4; ni++)
                acc[mi][ni] = __builtin_amdgcn_mfma_f32_16x16x32_bf16(
                    af[mi], bfr[ni], acc[mi][ni], 0, 0, 0);
        __syncthreads();
    }
    const float* b2e = b2 + (size_t)e * D_MODEL;
#pragma unroll
    for (int ni = 0; ni < 4; ni++) {
        int n = n0 + no + ni * 16 + lm;
        float bias = (blockIdx.z == 0) ? b2e[n] : 0.f;
#pragma unroll
        for (int mi = 0; mi < 4; mi++)
#pragma unroll
            for (int r = 0; r < 4; r++) {
                int m = mo + mi * 16 + quad * 4 + r;
                int tk = toks[m];
                if (tk >= 0) {
                    atomicAdd(&out[(size_t)tk * D_MODEL + n],
                              (acc[mi][ni][r] + bias) * wgt[tk]);
                }
            }
    }
}

// ---------------------------------------------------------------------------
extern "C" void kernel_launch(void* const* d_in, const int* in_sizes, int n_in,
                              void* d_out, int out_size, void* d_ws, size_t ws_size,
                              hipStream_t stream) {
    const float* x  = (const float*)d_in[0];
    const float* Wg = (const float*)d_in[1];
    const float* bg = (const float*)d_in[2];
    const float* W1 = (const float*)d_in[3];
    const float* b1 = (const float*)d_in[4];
    const float* W2 = (const float*)d_in[5];
    const float* b2 = (const float*)d_in[6];
    float* out = (float*)d_out;

    char* ws = (char*)d_ws;
    int*   counts = (int*)ws;                            // 32 B
    float* wgt    = (float*)(ws + 1024);                 // 16 KB
    int*   tlist  = (int*)(ws + 32768);                  // 128 KB
    unsigned short* h = (unsigned short*)(ws + 262144);  // 33.5 MB bf16
    unsigned short* W1t = (unsigned short*)(ws + 33816576);   // 67 MB bf16
    unsigned short* W2t = (unsigned short*)(ws + 100925440);  // 67 MB bf16
    const size_t WS_NEEDED = 168034304;

    hipMemsetAsync(counts, 0, NUM_EXPERTS * sizeof(int), stream);
    hipMemsetAsync(out, 0, (size_t)out_size * sizeof(float), stream);

    gate_kernel<<<NTOK / 4, 256, 0, stream>>>(x, Wg, bg, counts, tlist, wgt);

    if (ws_size >= WS_NEEDED) {
        // pre-pass: cvt+transpose weights to bf16 [E][N][K]
        cvt_transpose<<<dim3(D_HIDDEN / 64, D_MODEL / 64, NUM_EXPERTS), 256, 0, stream>>>(
            W1, W1t, D_MODEL, D_HIDDEN);
        cvt_transpose<<<dim3(D_MODEL / 64, D_HIDDEN / 64, NUM_EXPERTS), 256, 0, stream>>>(
            W2, W2t, D_HIDDEN, D_MODEL);
        ffn1_fast<<<dim3(D_HIDDEN / 128, MAXSLOT), 256, 0, stream>>>(
            x, W1t, b1, counts, tlist, h);
        ffn2_fast<<<dim3(D_MODEL / 128, MAXSLOT, KSPLIT), 256, 0, stream>>>(
            h, W2t, b2, counts, tlist, wgt, out);
    } else {
        ffn1_fb<<<dim3(D_HIDDEN / 128, MAXSLOT), 256, 0, stream>>>(
            x, W1, b1, counts, tlist, h);
        ffn2_fb<<<dim3(D_MODEL / 128, MAXSLOT, KSPLIT), 256, 0, stream>>>(
            h, W2, b2, counts, tlist, wgt, out);
    }
}